// Round 2
// baseline (244.755 us; speedup 1.0000x reference)
//
#include <hip/hip_runtime.h>
#include <hip/hip_bf16.h>

#define NBH 64
#define NSEQ 2048
#define DD 128
#define EPS 1e-6f
#define NCH 16          // phase-1 n-chunks per bh
#define CHROWS 128      // rows per phase-1 block

typedef __bf16 bf16x8 __attribute__((ext_vector_type(8)));
typedef __bf16 bf16x4 __attribute__((ext_vector_type(4)));
typedef float  f32x4  __attribute__((ext_vector_type(4)));

__device__ __forceinline__ float elu1(float x) {
    // elu(x)+1 = x+1 (x>0), exp(x) (x<=0)
    return x > 0.f ? x + 1.f : __expf(x);
}

// ---------------------------------------------------------------------------
// Phase 1: partial KV^T (bf16).  grid (16, 64), 256 thr, 3 blocks/CU.
// part[(bh*16+s)][e][d] = sum over 128 chunk rows n of Vf[n,e]*Kf[n,d]
// LDS transpose: KfT[d][n], VfT[e][n], stride 72 bf16, 64-row sub-tiles.
// Staging: thread t: rows (t&15)*4..+3, cols (t>>4)*8..+7 -> float4 global
// loads (full 128B line coverage per wave), ds_write_b64 bank-balanced.
// ---------------------------------------------------------------------------
__global__ __launch_bounds__(256, 3) void kv_partial_kernel(
    const float* __restrict__ K, const float* __restrict__ V,
    const float* __restrict__ mask, __bf16* __restrict__ part)
{
    __shared__ __bf16 KfT[128 * 72];
    __shared__ __bf16 VfT[128 * 72];
    __shared__ float  mloc[CHROWS];

    const int s  = blockIdx.x;
    const int bh = blockIdx.y;
    const int b  = bh >> 4;
    const int t  = threadIdx.x;
    const int n0 = s * CHROWS;

    if (t < CHROWS) mloc[t] = mask[b * NSEQ + n0 + t];
    __syncthreads();

    const int rg   = t & 15;      // staging rows rg*4..+3 (per 64-row sub)
    const int d0   = (t >> 4) * 8;// staging cols d0..d0+7
    const int lane = t & 63;
    const int w    = t >> 6;      // wave 0..3 -> e-tiles {2w, 2w+1}
    const int quad = lane >> 4;
    const int col  = lane & 15;

    f32x4 acc[2][8];
    #pragma unroll
    for (int i = 0; i < 2; ++i)
        #pragma unroll
        for (int dt = 0; dt < 8; ++dt) acc[i][dt] = (f32x4){0.f, 0.f, 0.f, 0.f};

    const float* Kb = K + ((size_t)bh * NSEQ + n0) * DD;
    const float* Vb = V + ((size_t)bh * NSEQ + n0) * DD;

    #pragma unroll
    for (int sub = 0; sub < 2; ++sub) {
        // load + transform 64 rows into regs (16 float4 global loads)
        bf16x4 kc[8], vc[8];
        #pragma unroll
        for (int j = 0; j < 4; ++j) {
            const int nl = sub * 64 + rg * 4 + j;
            const float m = mloc[nl];
            f32x4 klo = *(const f32x4*)&Kb[(size_t)nl * DD + d0];
            f32x4 khi = *(const f32x4*)&Kb[(size_t)nl * DD + d0 + 4];
            f32x4 vlo = *(const f32x4*)&Vb[(size_t)nl * DD + d0];
            f32x4 vhi = *(const f32x4*)&Vb[(size_t)nl * DD + d0 + 4];
            #pragma unroll
            for (int c = 0; c < 4; ++c) {
                kc[c][j]     = (__bf16)(elu1(klo[c]) * m);
                kc[4 + c][j] = (__bf16)(elu1(khi[c]) * m);
                vc[c][j]     = (__bf16)(vlo[c] * m);
                vc[4 + c][j] = (__bf16)(vhi[c] * m);
            }
        }
        __syncthreads();                       // prev MFMA done with LDS
        #pragma unroll
        for (int c = 0; c < 8; ++c) {
            *(bf16x4*)&KfT[(d0 + c) * 72 + rg * 4] = kc[c];
            *(bf16x4*)&VfT[(d0 + c) * 72 + rg * 4] = vc[c];
        }
        __syncthreads();
        #pragma unroll
        for (int kk = 0; kk < 2; ++kk) {
            const int k0 = kk * 32 + quad * 8;
            bf16x8 a0 = *(bf16x8*)&VfT[((2 * w)     * 16 + col) * 72 + k0];
            bf16x8 a1 = *(bf16x8*)&VfT[((2 * w + 1) * 16 + col) * 72 + k0];
            #pragma unroll
            for (int dt = 0; dt < 8; ++dt) {
                bf16x8 bb = *(bf16x8*)&KfT[(dt * 16 + col) * 72 + k0];
                acc[0][dt] = __builtin_amdgcn_mfma_f32_16x16x32_bf16(a0, bb, acc[0][dt], 0, 0, 0);
                acc[1][dt] = __builtin_amdgcn_mfma_f32_16x16x32_bf16(a1, bb, acc[1][dt], 0, 0, 0);
            }
        }
    }

    // store partial KV^T (bf16), layout [e][d]
    __bf16* po = part + ((size_t)(bh * NCH + s) << 14);
    #pragma unroll
    for (int i = 0; i < 2; ++i) {
        #pragma unroll
        for (int r = 0; r < 4; ++r) {
            const int e = (2 * w + i) * 16 + quad * 4 + r;
            #pragma unroll
            for (int dt = 0; dt < 8; ++dt)
                po[e * 128 + dt * 16 + col] = (__bf16)acc[i][dt][r];
        }
    }
}

// ---------------------------------------------------------------------------
// Phase 2: sum 16 bf16 partials -> bf16 KVT[bh][e][d].  512 blocks x 256 thr.
// ---------------------------------------------------------------------------
__global__ __launch_bounds__(256) void kv_reduce_kernel(
    const __bf16* __restrict__ part, __bf16* __restrict__ kvt)
{
    const int gid = blockIdx.x * 256 + threadIdx.x;   // 0..131071
    const int i   = gid * 8;
    const int bh  = i >> 14;
    const int ii  = i & 16383;
    const __bf16* p = part + (((size_t)bh * NCH) << 14) + ii;
    float sum[8] = {0.f, 0.f, 0.f, 0.f, 0.f, 0.f, 0.f, 0.f};
    #pragma unroll
    for (int s = 0; s < NCH; ++s) {
        bf16x8 v = *(const bf16x8*)(p + ((size_t)s << 14));
        #pragma unroll
        for (int c = 0; c < 8; ++c) sum[c] += (float)v[c];
    }
    bf16x8 o;
    #pragma unroll
    for (int c = 0; c < 8; ++c) o[c] = (__bf16)sum[c];
    *(bf16x8*)&kvt[i] = o;
}

// ---------------------------------------------------------------------------
// Phase 3: out = rmsnorm( Qf @ KV ).  grid (16, 64), 256 thr, 128 rows/block.
// Stage KVT (128x128 bf16) + Qf (128x128 bf16) once, single sync, MFMA, norm.
// ---------------------------------------------------------------------------
__global__ __launch_bounds__(256, 2) void qkv_norm_kernel(
    const float* __restrict__ Q, const __bf16* __restrict__ kvt,
    float* __restrict__ out)
{
    __shared__ __bf16 KVT[128 * 136];
    __shared__ __bf16 Qf[128 * 136];

    const int bh   = blockIdx.y;
    const int row0 = blockIdx.x * 128;
    const int t    = threadIdx.x;
    const int lane = t & 63;
    const int w    = t >> 6;     // wave 0..3 -> row-tiles {2w, 2w+1}
    const int quad = lane >> 4;
    const int col  = lane & 15;

    // stage KVT
    {
        const __bf16* src = kvt + ((size_t)bh << 14);
        #pragma unroll
        for (int i = 0; i < 8; ++i) {
            const int idx = i * 256 + t;       // granule id 0..2047
            const int e   = idx >> 4;
            const int dd  = (idx & 15) * 8;
            *(bf16x8*)&KVT[e * 136 + dd] = *(const bf16x8*)&src[e * 128 + dd];
        }
    }
    // stage Qf = elu(Q)+1
    {
        const float* Qb = Q + ((size_t)bh * NSEQ + row0) * DD;
        const int qr  = t >> 1;
        const int qd0 = (t & 1) * 64;
        #pragma unroll
        for (int j = 0; j < 16; ++j) {
            f32x4 q = *(const f32x4*)&Qb[(size_t)qr * DD + qd0 + j * 4];
            bf16x4 qq;
            qq[0] = (__bf16)elu1(q[0]); qq[1] = (__bf16)elu1(q[1]);
            qq[2] = (__bf16)elu1(q[2]); qq[3] = (__bf16)elu1(q[3]);
            *(bf16x4*)&Qf[qr * 136 + qd0 + j * 4] = qq;
        }
    }
    __syncthreads();

    f32x4 acc[2][8];
    #pragma unroll
    for (int i = 0; i < 2; ++i)
        #pragma unroll
        for (int et = 0; et < 8; ++et) acc[i][et] = (f32x4){0.f, 0.f, 0.f, 0.f};

    #pragma unroll
    for (int kk = 0; kk < 4; ++kk) {
        const int k0 = kk * 32 + quad * 8;
        bf16x8 a0 = *(bf16x8*)&Qf[((2 * w)     * 16 + col) * 136 + k0];
        bf16x8 a1 = *(bf16x8*)&Qf[((2 * w + 1) * 16 + col) * 136 + k0];
        #pragma unroll
        for (int et = 0; et < 8; ++et) {
            bf16x8 bb = *(bf16x8*)&KVT[(et * 16 + col) * 136 + k0];
            acc[0][et] = __builtin_amdgcn_mfma_f32_16x16x32_bf16(a0, bb, acc[0][et], 0, 0, 0);
            acc[1][et] = __builtin_amdgcn_mfma_f32_16x16x32_bf16(a1, bb, acc[1][et], 0, 0, 0);
        }
    }

    // RMS norm per row + store.  C layout: row = quad*4+reg, col = lane&15.
    float* ob = out + ((size_t)bh * NSEQ + row0) * DD;
    #pragma unroll
    for (int i = 0; i < 2; ++i) {
        #pragma unroll
        for (int r = 0; r < 4; ++r) {
            float p = 0.f;
            #pragma unroll
            for (int et = 0; et < 8; ++et) p += acc[i][et][r] * acc[i][et][r];
            p += __shfl_xor(p, 1);
            p += __shfl_xor(p, 2);
            p += __shfl_xor(p, 4);
            p += __shfl_xor(p, 8);
            const float scale = rsqrtf(p * (1.0f / 128.0f) + EPS);
            const int row = (2 * w + i) * 16 + quad * 4 + r;
            #pragma unroll
            for (int et = 0; et < 8; ++et)
                ob[row * DD + et * 16 + col] = acc[i][et][r] * scale;
        }
    }
}

extern "C" void kernel_launch(void* const* d_in, const int* in_sizes, int n_in,
                              void* d_out, int out_size, void* d_ws, size_t ws_size,
                              hipStream_t stream) {
    const float* Q    = (const float*)d_in[0];
    const float* K    = (const float*)d_in[1];
    const float* V    = (const float*)d_in[2];
    const float* mask = (const float*)d_in[3];
    float* out = (float*)d_out;

    __bf16* part = (__bf16*)d_ws;                                  // 32 MB
    __bf16* kvt  = part + (size_t)NBH * NCH * 16384;               // 2 MB

    kv_partial_kernel<<<dim3(NCH, NBH), 256, 0, stream>>>(K, V, mask, part);
    kv_reduce_kernel<<<512, 256, 0, stream>>>(part, kvt);
    qkv_norm_kernel<<<dim3(16, NBH), 256, 0, stream>>>(Q, kvt, out);
}

// Round 3
// 242.642 us; speedup vs baseline: 1.0087x; 1.0087x over previous
//
#include <hip/hip_runtime.h>
#include <hip/hip_bf16.h>

#define NBH 64
#define NSEQ 2048
#define DD 128
#define EPS 1e-6f
#define NCH 8            // phase-1 chunks per bh (256 rows each)
#define G1 260           // p1 LDS granule stride: 2 rows fp32 (256) + 4 pad
#define G3 260           // p3 Q granule stride (same scheme)
#define KVG 264          // p3 KVT bf16 granule stride: 2 rows (256) + 8 pad
#define IMG_BYTES 33792  // 64 granules * 528 B  (KVT padded image per bh)

typedef __bf16 bf16x8 __attribute__((ext_vector_type(8)));
typedef float  f32x4  __attribute__((ext_vector_type(4)));

__device__ __forceinline__ float elu1(float x) {
    return x > 0.f ? x + 1.f : __expf(x);
}

// fire-and-forget global->LDS DMA, 16 B/lane, lands at ldsbase + lane*16
__device__ __forceinline__ void dma16(const void* g, void* l) {
    __builtin_amdgcn_global_load_lds(
        (const __attribute__((address_space(1))) unsigned int*)g,
        (__attribute__((address_space(3))) unsigned int*)l, 16, 0, 0);
}

// ---------------------------------------------------------------------------
// Phase 1: partial KVT[e][d] (bf16).  grid (8, 64), 256 thr, 2 blocks/CU.
// 8 passes of 32 rows; raw fp32 K/V DMA'd into double-buffered LDS;
// transpose happens at fragment read (scalar ds_read_b32, conflict-free by
// granule pad).  mask folded as m^2 into K side.
// ---------------------------------------------------------------------------
__global__ __launch_bounds__(256, 2) void kv_partial_kernel(
    const float* __restrict__ K, const float* __restrict__ V,
    const float* __restrict__ mask, __bf16* __restrict__ part)
{
    __shared__ __align__(16) float Kls[2][16 * G1];
    __shared__ __align__(16) float Vls[2][16 * G1];
    __shared__ float m2[256];

    const int s  = blockIdx.x;
    const int bh = blockIdx.y;
    const int b  = bh >> 4;
    const int t  = threadIdx.x;
    const int n0 = s * 256;

    { float m = mask[b * NSEQ + n0 + t]; m2[t] = m * m; }

    const int lane = t & 63;
    const int w    = t >> 6;          // wave 0..3
    const int quad = lane >> 4;
    const int col  = lane & 15;

    const float* Kb = K + ((size_t)bh * NSEQ + n0) * DD;
    const float* Vb = V + ((size_t)bh * NSEQ + n0) * DD;

    const int lrow = lane >> 5;          // DMA: lane's row within granule
    const int lc4  = (lane & 31) * 4;    // DMA: lane's fp32 col

    f32x4 acc[2][8];
    #pragma unroll
    for (int i = 0; i < 2; ++i)
        #pragma unroll
        for (int dt = 0; dt < 8; ++dt) acc[i][dt] = (f32x4){0.f, 0.f, 0.f, 0.f};

    // ---- prologue: DMA pass 0 into buf 0 (wave w: granules w*4..w*4+3) ----
    #pragma unroll
    for (int i = 0; i < 4; ++i) {
        const int g   = w * 4 + i;
        const int row = g * 2 + lrow;    // pass-0 rows
        dma16(Kb + (size_t)row * DD + lc4, &Kls[0][g * G1]);
        dma16(Vb + (size_t)row * DD + lc4, &Vls[0][g * G1]);
    }

    for (int p = 0; p < 8; ++p) {
        const int buf = p & 1;
        __syncthreads();   // drains pass-p DMA; buf[(p+1)&1] readers done

        if (p < 7) {
            const int nb = (p + 1) & 1;
            #pragma unroll
            for (int i = 0; i < 4; ++i) {
                const int g   = w * 4 + i;
                const int row = (p + 1) * 32 + g * 2 + lrow;
                dma16(Kb + (size_t)row * DD + lc4, &Kls[nb][g * G1]);
                dma16(Vb + (size_t)row * DD + lc4, &Vls[nb][g * G1]);
            }
        }

        // ---- compute pass p: one MFMA k-step (k = 32 rows) ----
        // A-frags (V side, raw): e-tiles {2w, 2w+1}
        bf16x8 a[2];
        #pragma unroll
        for (int i = 0; i < 2; ++i) {
            const int e = (2 * w + i) * 16 + col;
            #pragma unroll
            for (int j = 0; j < 8; ++j) {
                const int r = quad * 8 + j;
                a[i][j] = (__bf16)Vls[buf][(r >> 1) * G1 + (r & 1) * 128 + e];
            }
        }
        float mm[8];
        #pragma unroll
        for (int j = 0; j < 8; ++j) mm[j] = m2[p * 32 + quad * 8 + j];

        #pragma unroll
        for (int dt = 0; dt < 8; ++dt) {
            bf16x8 bfrag;
            #pragma unroll
            for (int j = 0; j < 8; ++j) {
                const int r = quad * 8 + j;
                const float k = Kls[buf][(r >> 1) * G1 + (r & 1) * 128 + dt * 16 + col];
                bfrag[j] = (__bf16)(elu1(k) * mm[j]);
            }
            acc[0][dt] = __builtin_amdgcn_mfma_f32_16x16x32_bf16(a[0], bfrag, acc[0][dt], 0, 0, 0);
            acc[1][dt] = __builtin_amdgcn_mfma_f32_16x16x32_bf16(a[1], bfrag, acc[1][dt], 0, 0, 0);
        }
    }

    // ---- store partial KVT (bf16, natural [e][d]) ----
    __bf16* po = part + ((size_t)(bh * NCH + s) << 14);
    #pragma unroll
    for (int i = 0; i < 2; ++i)
        #pragma unroll
        for (int r = 0; r < 4; ++r) {
            const int e = (2 * w + i) * 16 + quad * 4 + r;
            #pragma unroll
            for (int dt = 0; dt < 8; ++dt)
                po[e * 128 + dt * 16 + col] = (__bf16)acc[i][dt][r];
        }
}

// ---------------------------------------------------------------------------
// Phase 2: sum 8 bf16 partials -> padded bf16 KVT image (DMA-copyable layout:
// 2-row granules of 512 B + 16 B pad).  512 blocks x 256 thr.
// ---------------------------------------------------------------------------
__global__ __launch_bounds__(256) void kv_reduce_kernel(
    const __bf16* __restrict__ part, __bf16* __restrict__ img)
{
    const int gid = blockIdx.x * 256 + threadIdx.x;  // 0..131071
    const int d8  = gid & 15;          // 8-elem d group
    const int e   = (gid >> 4) & 127;
    const int bh  = gid >> 11;

    const __bf16* p = part + (((size_t)bh * NCH) << 14) + e * 128 + d8 * 8;
    float sum[8] = {0.f, 0.f, 0.f, 0.f, 0.f, 0.f, 0.f, 0.f};
    #pragma unroll
    for (int s = 0; s < NCH; ++s) {
        bf16x8 v = *(const bf16x8*)(p + ((size_t)s << 14));
        #pragma unroll
        for (int c = 0; c < 8; ++c) sum[c] += (float)v[c];
    }
    bf16x8 o;
    #pragma unroll
    for (int c = 0; c < 8; ++c) o[c] = (__bf16)sum[c];
    __bf16* dst = img + (size_t)bh * (IMG_BYTES / 2)
                + (e >> 1) * KVG + (e & 1) * 128 + d8 * 8;
    *(bf16x8*)dst = o;
}

// ---------------------------------------------------------------------------
// Phase 3: out = rmsnorm( elu1(Q) @ KV ).  grid (8, 64), 128 thr (2 waves),
// 2 blocks/CU.  KVT image DMA'd once; Q streamed in 32-row double-buffered
// passes.  B-frags are direct ds_read_b128 bf16 (no cvt).
// ---------------------------------------------------------------------------
__global__ __launch_bounds__(128, 2) void qkv_norm_kernel(
    const float* __restrict__ Q, const __bf16* __restrict__ img,
    float* __restrict__ out)
{
    __shared__ __align__(16) float  Qls[2][16 * G3];
    __shared__ __align__(16) __bf16 KVls[64 * KVG];   // 33792 B

    const int bh   = blockIdx.y;
    const int row0 = blockIdx.x * 256;
    const int t    = threadIdx.x;
    const int lane = t & 63;
    const int w    = t >> 6;          // wave 0..1 -> row-tile w of each pass
    const int quad = lane >> 4;
    const int col  = lane & 15;

    const float* Qb = Q + ((size_t)bh * NSEQ + row0) * DD;
    const char*  ib = (const char*)img + (size_t)bh * IMG_BYTES;

    const int lrow = lane >> 5;
    const int lc4  = (lane & 31) * 4;

    // ---- prologue DMA: KVT image (33 x 1 KB chunks) + Q pass 0 ----
    {
        const int c0 = w ? 17 : 0;
        const int c1 = w ? 33 : 17;
        for (int c = c0; c < c1; ++c)
            dma16(ib + c * 1024 + lane * 16, (char*)KVls + c * 1024);
        #pragma unroll
        for (int i = 0; i < 8; ++i) {
            const int g   = w * 8 + i;
            const int row = g * 2 + lrow;
            dma16(Qb + (size_t)row * DD + lc4, &Qls[0][g * G3]);
        }
    }

    for (int p = 0; p < 8; ++p) {
        const int buf = p & 1;
        __syncthreads();

        if (p < 7) {
            const int nb = (p + 1) & 1;
            #pragma unroll
            for (int i = 0; i < 8; ++i) {
                const int g   = w * 8 + i;
                const int row = (p + 1) * 32 + g * 2 + lrow;
                dma16(Qb + (size_t)row * DD + lc4, &Qls[nb][g * G3]);
            }
        }

        // ---- compute: wave w -> rows p*32 + w*16 .. +15, full e ----
        f32x4 acc[8];
        #pragma unroll
        for (int et = 0; et < 8; ++et) acc[et] = (f32x4){0.f, 0.f, 0.f, 0.f};

        const int rloc = w * 16 + col;    // A-frag row within pass
        #pragma unroll
        for (int kk = 0; kk < 4; ++kk) {
            bf16x8 a;
            #pragma unroll
            for (int j = 0; j < 8; ++j) {
                const int d = kk * 32 + quad * 8 + j;
                a[j] = (__bf16)elu1(Qls[buf][(rloc >> 1) * G3 + (rloc & 1) * 128 + d]);
            }
            #pragma unroll
            for (int et = 0; et < 8; ++et) {
                const int e = et * 16 + col;
                bf16x8 bb = *(const bf16x8*)&KVls[(e >> 1) * KVG + (e & 1) * 128
                                                  + kk * 32 + quad * 8];
                acc[et] = __builtin_amdgcn_mfma_f32_16x16x32_bf16(a, bb, acc[et], 0, 0, 0);
            }
        }

        // ---- RMS norm + store.  C layout: row = quad*4+reg, col = lane&15 ----
        float* ob = out + ((size_t)bh * NSEQ + row0 + p * 32 + w * 16) * DD;
        #pragma unroll
        for (int r = 0; r < 4; ++r) {
            float ps = 0.f;
            #pragma unroll
            for (int et = 0; et < 8; ++et) ps += acc[et][r] * acc[et][r];
            ps += __shfl_xor(ps, 1);
            ps += __shfl_xor(ps, 2);
            ps += __shfl_xor(ps, 4);
            ps += __shfl_xor(ps, 8);
            const float scale = rsqrtf(ps * (1.0f / 128.0f) + EPS);
            const int row = quad * 4 + r;
            #pragma unroll
            for (int et = 0; et < 8; ++et)
                ob[row * DD + et * 16 + col] = acc[et][r] * scale;
        }
    }
}

extern "C" void kernel_launch(void* const* d_in, const int* in_sizes, int n_in,
                              void* d_out, int out_size, void* d_ws, size_t ws_size,
                              hipStream_t stream) {
    const float* Q    = (const float*)d_in[0];
    const float* K    = (const float*)d_in[1];
    const float* V    = (const float*)d_in[2];
    const float* mask = (const float*)d_in[3];
    float* out = (float*)d_out;

    __bf16* part = (__bf16*)d_ws;                                   // 16 MB
    __bf16* img  = (__bf16*)((char*)d_ws + (size_t)NBH * NCH * 16384 * 2);

    kv_partial_kernel<<<dim3(NCH, NBH), 256, 0, stream>>>(K, V, mask, part);
    kv_reduce_kernel<<<512, 256, 0, stream>>>(part, img);
    qkv_norm_kernel<<<dim3(8, NBH), 128, 0, stream>>>(Q, img, out);
}